// Round 12
// baseline (165.330 us; speedup 1.0000x reference)
//
#include <hip/hip_runtime.h>
#include <hip/hip_bf16.h>

typedef __bf16 bf16x8  __attribute__((ext_vector_type(8)));
typedef __bf16 bf16x16 __attribute__((ext_vector_type(16)));
typedef float  f32x4   __attribute__((ext_vector_type(4)));

#define N_IN   4096
#define N_OUT  1024
#define BATCH  16
#define ROWS   16

// LDS strides in __bf16 elements
#define H1_STR   72     // fallback kernel only
#define H2_STR   72
#define FT_JSTR  40     // 32 + 8  (i-stride inside a j-row of half-ftv)
#define FTH_NSTR 640    // 16*40 (half: 16 j's per pass)
#define G_STR    520    // 512 + 8
#define V_STR    520

// ws layout:
//   [0,131072)       w3t  bf16 (1024x64)       w3t[col*64+k]
//   [131072,139264)  w2t  bf16 (64x64)         w2t[col*64+k]
//   [139264,4333568) featT bf16 (32*4096*16)   featT[((c*4096+src)*16)+b]
#define WS_W3T_OFF    0
#define WS_W2T_OFF    131072
#define WS_FEATT_OFF  139264
#define WS_NEED       4333568

__global__ void qc_zero_kernel(float* __restrict__ out, int n4) {
    int i = blockIdx.x * blockDim.x + threadIdx.x;
    if (i < n4) ((float4*)out)[i] = make_float4(0.f, 0.f, 0.f, 0.f);
}

// Fallback prep: w3t/w2t only
__global__ void qc_prep_kernel(const float* __restrict__ w3, const float* __restrict__ w2,
                               __bf16* __restrict__ w3t, __bf16* __restrict__ w2t) {
    int gid = blockIdx.x * blockDim.x + threadIdx.x;
    if (gid < 65536) {
        int k = gid & 63, col = gid >> 6;
        w3t[gid] = (__bf16)w3[k * 1024 + col];
    } else {
        int j = gid - 65536;
        int k = j & 63, col = j >> 6;
        w2t[j] = (__bf16)w2[k * 64 + col];
    }
}

// Fused prep: zero out (512 blks) + w3t (256) + w2t (16) + featT transpose (512)
__global__ void qc_prep2_kernel(const float* __restrict__ w3, const float* __restrict__ w2,
                                const float* __restrict__ feat,
                                float* __restrict__ out,
                                __bf16* __restrict__ w3t, __bf16* __restrict__ w2t,
                                __bf16* __restrict__ featT) {
    int bid = blockIdx.x, tid = threadIdx.x;
    if (bid < 512) {
        int i = bid * 256 + tid;                     // 131072 float4s
        ((float4*)out)[i] = make_float4(0.f, 0.f, 0.f, 0.f);
    } else if (bid < 768) {
        int gid = (bid - 512) * 256 + tid;           // 65536
        int k = gid & 63, col = gid >> 6;
        w3t[gid] = (__bf16)w3[k * 1024 + col];
    } else if (bid < 784) {
        int j = (bid - 768) * 256 + tid;             // 4096
        int k = j & 63, col = j >> 6;
        w2t[j] = (__bf16)w2[k * 64 + col];
    } else {
        // featT[c][src][b] = feat[b][c][src]; 512 blocks cover 32 c x 16 chunks
        int bid2 = bid - 784;                        // 0..511
        int c    = bid2 >> 4;                        // 0..31
        int src  = (bid2 & 15) * 256 + tid;          // 0..4095
        bf16x16 v;
        #pragma unroll
        for (int b = 0; b < 16; ++b)                 // coalesced dword loads per b
            v[b] = (__bf16)feat[(b * 32 + c) * N_IN + src];
        __bf16* p = &featT[((size_t)c * N_IN + src) * 16];   // 32B/thread, coalesced
        *(bf16x8*)p       = *(bf16x8*)&v;
        *(bf16x8*)(p + 8) = *((bf16x8*)&v + 1);
    }
}

// ---------------------------------------------------------------------------
// Fused kernel: 512 threads per 16-row tile, 5 barriers, 40448 B LDS.
//   gather issue + h1-in-regs + h2 (MFMA) -> S2 -> C-pass0 (j<16) -> park ->
//   S3a -> D0 -> S3b -> C-pass1 -> S3c -> D1 + vals overlay -> S4 ->
//   Phase E: run-merge + bounded backward window walk. Emission by run END:
//   - middles: interior plain store
//   - head run of a window with boundary: chained total; store/atomic
//   - tail run ending at window boundary (next window differs): store/atomic
//   - w==31 tail: atomicAdd (may continue into next block)
// ---------------------------------------------------------------------------
__global__ __launch_bounds__(512, 6)
void qc_fused_kernel(const __bf16* __restrict__ featT,
                     const float* __restrict__ w1,
                     const float* __restrict__ locs,
                     const int*   __restrict__ eidx,
                     const __bf16* __restrict__ w2t,
                     const __bf16* __restrict__ w3t,
                     float* __restrict__ out,
                     int E)
{
    __shared__ __align__(16) __bf16 h2b[ROWS * H2_STR];    // 2304 B
    __shared__ __align__(16) __bf16 ftv[ROWS * FTH_NSTR];  // 20480 B
    __shared__ __align__(16) __bf16 gb [BATCH * G_STR];    // 16640 B (later: vals)
    __shared__ unsigned short seg_s[512];                  // 1024 B
    // total 40448 B

    const int tid = threadIdx.x;
    const int n0  = blockIdx.x * ROWS;
    const int t0  = n0 * 32;
    const int ch0 = t0 / E;
    const int m0  = t0 - ch0 * E;          // block spans <512 t's -> at most one wrap

    // ---- Gather: ONE 32B load per thread (all 16 batches), issued first ----
    int mm = m0 + tid;
    const int cc = ch0 + (mm >= E);
    if (mm >= E) mm -= E;
    int2 p = ((const int2*)eidx)[mm];      // .x = seg, .y = src
    bf16x16 gv = {};
    if (cc < 32)
        gv = *(const bf16x16*)&featT[((size_t)cc * N_IN + p.y) * 16];
    seg_s[tid] = (unsigned short)p.x;

    const int lane = tid & 63;
    const int wv   = tid >> 6;      // 0..7
    const int ml   = lane & 15;
    const int q    = lane >> 4;

    // ---- Phase B (waves 0..3): h1 in registers (A-frag layout), h2 via MFMA ----
    if (wv < 4) {
        int n = n0 + ml;
        float lx = 0.f, ly = 0.f;
        if (n < E) { lx = locs[n * 2]; ly = locs[n * 2 + 1]; }
        bf16x8 a0, a1;
        {
            const int c0_ = q * 8;
            float4 wa0 = *(const float4*)&w1[c0_];
            float4 wa1 = *(const float4*)&w1[c0_ + 4];
            float4 wb0 = *(const float4*)&w1[64 + c0_];
            float4 wb1 = *(const float4*)&w1[64 + c0_ + 4];
            a0[0] = (__bf16)__sinf(lx * wa0.x + ly * wb0.x);
            a0[1] = (__bf16)__sinf(lx * wa0.y + ly * wb0.y);
            a0[2] = (__bf16)__sinf(lx * wa0.z + ly * wb0.z);
            a0[3] = (__bf16)__sinf(lx * wa0.w + ly * wb0.w);
            a0[4] = (__bf16)__sinf(lx * wa1.x + ly * wb1.x);
            a0[5] = (__bf16)__sinf(lx * wa1.y + ly * wb1.y);
            a0[6] = (__bf16)__sinf(lx * wa1.z + ly * wb1.z);
            a0[7] = (__bf16)__sinf(lx * wa1.w + ly * wb1.w);
            float4 wc0 = *(const float4*)&w1[32 + c0_];
            float4 wc1 = *(const float4*)&w1[32 + c0_ + 4];
            float4 wd0 = *(const float4*)&w1[96 + c0_];
            float4 wd1 = *(const float4*)&w1[96 + c0_ + 4];
            a1[0] = (__bf16)__sinf(lx * wc0.x + ly * wd0.x);
            a1[1] = (__bf16)__sinf(lx * wc0.y + ly * wd0.y);
            a1[2] = (__bf16)__sinf(lx * wc0.z + ly * wd0.z);
            a1[3] = (__bf16)__sinf(lx * wc0.w + ly * wd0.w);
            a1[4] = (__bf16)__sinf(lx * wc1.x + ly * wd1.x);
            a1[5] = (__bf16)__sinf(lx * wc1.y + ly * wd1.y);
            a1[6] = (__bf16)__sinf(lx * wc1.z + ly * wd1.z);
            a1[7] = (__bf16)__sinf(lx * wc1.w + ly * wd1.w);
        }
        const __bf16* wp = &w2t[(wv * 16 + ml) * 64 + q * 8];
        bf16x8 b0 = *(const bf16x8*)wp;
        bf16x8 b1 = *(const bf16x8*)(wp + 32);
        f32x4 c = {0.f, 0.f, 0.f, 0.f};
        c = __builtin_amdgcn_mfma_f32_16x16x32_bf16(a0, b0, c, 0, 0, 0);
        c = __builtin_amdgcn_mfma_f32_16x16x32_bf16(a1, b1, c, 0, 0, 0);
        #pragma unroll
        for (int g_ = 0; g_ < 4; ++g_)
            h2b[(q * 4 + g_) * H2_STR + wv * 16 + ml] = (__bf16)__sinf(c[g_]);
    }
    __syncthreads();   // S2

    // A-operand fragments of h2 (reused in both C passes)
    bf16x8 ha0 = *(const bf16x8*)&h2b[ml * H2_STR + q * 8];
    bf16x8 ha1 = *(const bf16x8*)&h2b[ml * H2_STR + 32 + q * 8];

    bf16x8 ag[2];
    f32x4  c0[2], c1[2];

    // ---- C-pass0: filt cols j<16 -> ftv[n][j][i] (j = ml) ----
    #pragma unroll
    for (int tt = 0; tt < 4; ++tt) {
        int i_  = wv * 4 + tt;                 // 0..31
        int col = i_ * 32 + ml;                // j = ml < 16
        const __bf16* wp = &w3t[col * 64 + q * 8];
        bf16x8 b0 = *(const bf16x8*)wp;
        bf16x8 b1 = *(const bf16x8*)(wp + 32);
        f32x4 c = {0.f, 0.f, 0.f, 0.f};
        c = __builtin_amdgcn_mfma_f32_16x16x32_bf16(ha0, b0, c, 0, 0, 0);
        c = __builtin_amdgcn_mfma_f32_16x16x32_bf16(ha1, b1, c, 0, 0, 0);
        __bf16* fp = &ftv[ml * FT_JSTR + i_];
        fp[(q * 4 + 0) * FTH_NSTR] = (__bf16)c[0];
        fp[(q * 4 + 1) * FTH_NSTR] = (__bf16)c[1];
        fp[(q * 4 + 2) * FTH_NSTR] = (__bf16)c[2];
        fp[(q * 4 + 3) * FTH_NSTR] = (__bf16)c[3];
    }
    // ---- Park gathered batches into gb (gather had B + C-pass0 to drain) ----
    #pragma unroll
    for (int b = 0; b < 16; ++b)
        gb[b * G_STR + tid] = gv[b];
    __syncthreads();   // S3a

    // ---- D-pass0: load ag + f0, MFMA c0 (j = ml) ----
    {
        bf16x8 f0[2];
        #pragma unroll
        for (int rr = 0; rr < 2; ++rr) {
            int r = wv * 2 + rr;
            f0[rr] = *(const bf16x8*)&ftv[r * FTH_NSTR + ml * FT_JSTR + q * 8];
            ag[rr] = *(const bf16x8*)&gb[ml * G_STR + r * 32 + q * 8];
        }
        #pragma unroll
        for (int rr = 0; rr < 2; ++rr) {
            f32x4 z = {0.f, 0.f, 0.f, 0.f};
            c0[rr] = __builtin_amdgcn_mfma_f32_16x16x32_bf16(ag[rr], f0[rr], z, 0, 0, 0);
        }
    }
    __syncthreads();   // S3b: all ftv/gb reads done

    // ---- C-pass1: filt cols j>=16 -> ftv (overwrite; store at j-16) ----
    #pragma unroll
    for (int tt = 0; tt < 4; ++tt) {
        int i_  = wv * 4 + tt;
        int col = i_ * 32 + 16 + ml;           // j = 16 + ml
        const __bf16* wp = &w3t[col * 64 + q * 8];
        bf16x8 b0 = *(const bf16x8*)wp;
        bf16x8 b1 = *(const bf16x8*)(wp + 32);
        f32x4 c = {0.f, 0.f, 0.f, 0.f};
        c = __builtin_amdgcn_mfma_f32_16x16x32_bf16(ha0, b0, c, 0, 0, 0);
        c = __builtin_amdgcn_mfma_f32_16x16x32_bf16(ha1, b1, c, 0, 0, 0);
        __bf16* fp = &ftv[ml * FT_JSTR + i_];
        fp[(q * 4 + 0) * FTH_NSTR] = (__bf16)c[0];
        fp[(q * 4 + 1) * FTH_NSTR] = (__bf16)c[1];
        fp[(q * 4 + 2) * FTH_NSTR] = (__bf16)c[2];
        fp[(q * 4 + 3) * FTH_NSTR] = (__bf16)c[3];
    }
    __syncthreads();   // S3c

    // ---- D-pass1: load f1, MFMA c1 (j = 16+ml); vals overlay gb ----
    {
        bf16x8 f1[2];
        #pragma unroll
        for (int rr = 0; rr < 2; ++rr) {
            int r = wv * 2 + rr;
            f1[rr] = *(const bf16x8*)&ftv[r * FTH_NSTR + ml * FT_JSTR + q * 8];
        }
        #pragma unroll
        for (int rr = 0; rr < 2; ++rr) {
            f32x4 z = {0.f, 0.f, 0.f, 0.f};
            c1[rr] = __builtin_amdgcn_mfma_f32_16x16x32_bf16(ag[rr], f1[rr], z, 0, 0, 0);
        }
        __bf16* valsb = gb;
        #pragma unroll
        for (int rr = 0; rr < 2; ++rr) {
            int r = wv * 2 + rr;
            __bf16* vp = &valsb[r * 32];
            #pragma unroll
            for (int g_ = 0; g_ < 4; ++g_) {
                int b = q * 4 + g_;
                vp[b * V_STR + ml]      = (__bf16)c0[rr][g_];
                vp[b * V_STR + 16 + ml] = (__bf16)c1[rr][g_];
            }
        }
    }
    __syncthreads();   // S4

    // ---- Phase E: run-merge + bounded backward window walk ----
    // thread = (b, window w of 16 tl); the 32 windows of one b = one 32-lane
    // shfl group (tid = b*32 + w). Emission by where the run ENDS.
    {
        const __bf16* valsb = gb;
        const int b   = tid >> 5;            // 0..15
        const int w   = tid & 31;            // window index
        const int tl0 = w * 16;
        const __bf16* vp = &valsb[b * V_STR + tl0];
        bf16x8 v0 = *(const bf16x8*)(vp);
        bf16x8 v1 = *(const bf16x8*)(vp + 8);
        float vv[16];
        #pragma unroll
        for (int j = 0; j < 8; ++j) { vv[j] = (float)v0[j]; vv[8 + j] = (float)v1[j]; }

        // local serial merge over 16 elems (middles: sole-writer plain store)
        int fk = 0; float fs = 0.f; int nb = 0;
        int curKey; float curSum;
        {
            int mm2 = m0 + tl0; int cc2 = ch0 + (mm2 >= E);
            curKey = (cc2 < 32) ? ((cc2 << 10) | (int)seg_s[tl0]) : -1;
            curSum = vv[0];
        }
        #pragma unroll
        for (int j = 1; j < 16; ++j) {
            int mm2 = m0 + tl0 + j; int cc2 = ch0 + (mm2 >= E);
            int k = (cc2 < 32) ? ((cc2 << 10) | (int)seg_s[tl0 + j]) : -1;
            if (k != curKey) {
                if (nb == 0) { fk = curKey; fs = curSum; }
                else if (curKey >= 0) out[(b << 15) | curKey] = curSum;
                ++nb;
                curKey = k; curSum = vv[j];
            } else {
                curSum += vv[j];
            }
        }
        const int   lk    = curKey;
        const float ls    = curSum;
        const int   hasBi = (nb > 0) ? 1 : 0;
        if (!hasBi) { fk = lk; fs = ls; }

        // neighbor info (after fk finalization)
        int plk = __shfl_up(fk == lk && !hasBi ? lk : lk, 1, 32);   // lk of w-1
        int nfk = __shfl_down(fk, 1, 32);                            // fk of w+1
        bool headCont = (w > 0) && (fk == plk);
        bool nextCont = (w < 31) && (lk == nfk);

        // backward walk: sum tail pieces of my head run across prev windows.
        // Run length <= 64 (8x8 grid support) => <= 4 prev windows; 6 is safe.
        float add = 0.f;
        bool edgeStart = (w == 0);           // head run touches tl=0
        {
            bool walking = headCont;
            int  ww = w - 1;
            for (int it = 0; it < 6; ++it) {
                int idx = ww & 31;
                float s2 = __shfl(ls, idx, 32);
                int   h2 = __shfl(hasBi, idx, 32);
                int   k2 = __shfl(lk, idx, 32);
                int   kp = __shfl(lk, (idx - 1) & 31, 32);
                if (walking) {
                    add += s2;
                    if (h2)            { walking = false; }                   // started inside ww
                    else if (ww == 0)  { walking = false; edgeStart = true; } // started at tl=0
                    else if (k2 != kp) { walking = false; }                   // started at ww's window start
                    else               { --ww; }
                }
            }
        }

        // (1) head run ends inside my window (at first boundary)
        if (hasBi && fk >= 0) {
            float total = fs + (headCont ? add : 0.f);
            float* dst = &out[(b << 15) | fk];
            if (edgeStart) atomicAdd(dst, total);
            else           *dst = total;
        }
        // (2) tail run ends exactly at my window end (next window differs)
        if (w < 31 && !nextCont && lk >= 0) {
            if (hasBi) {
                out[(b << 15) | lk] = ls;          // starts inside w -> interior
            } else {
                float total = ls + (headCont ? add : 0.f);
                float* dst = &out[(b << 15) | lk];
                if (edgeStart) atomicAdd(dst, total);
                else           *dst = total;
            }
        }
        // (3) block-tail run (ends at tl=511; may continue into next block)
        if (w == 31 && lk >= 0) {
            float total = hasBi ? ls : (ls + (headCont ? add : 0.f));
            atomicAdd(&out[(b << 15) | lk], total);
        }
    }
}

// ---------------------------------------------------------------------------
// Fallback: round-1 fused kernel (used only if ws too small)
// ---------------------------------------------------------------------------
#define FB_FT_NSTR 1288
__global__ __launch_bounds__(256, 2)
void qc_main_kernel(const float* __restrict__ feat,
                    const float* __restrict__ w1,
                    const float* __restrict__ w2,
                    const float* __restrict__ locs,
                    const int*   __restrict__ eidx,
                    const __bf16* __restrict__ w3t,
                    float* __restrict__ out,
                    int E)
{
    __shared__ __align__(16) __bf16 h1b[ROWS * H1_STR];
    __shared__ __align__(16) __bf16 h2b[ROWS * H2_STR];
    __shared__ __align__(16) __bf16 ftv[ROWS * FB_FT_NSTR];
    __shared__ __align__(16) __bf16 gb [BATCH * G_STR];
    __shared__ unsigned short seg_s[512];
    __shared__ unsigned short src_s[512];

    const int tid = threadIdx.x;
    const int n0  = blockIdx.x * ROWS;
    const int t0  = n0 * 32;
    const int ch0 = t0 / E;
    const int m0  = t0 - ch0 * E;

    {
        const int r  = tid >> 4;
        const int j0 = (tid & 15) * 4;
        float lx = 0.f, ly = 0.f;
        int n = n0 + r;
        if (n < E) { lx = locs[n * 2]; ly = locs[n * 2 + 1]; }
        float4 wa = *(const float4*)&w1[j0];
        float4 wb = *(const float4*)&w1[64 + j0];
        __bf16* h = &h1b[r * H1_STR + j0];
        h[0] = (__bf16)__sinf(lx * wa.x + ly * wb.x);
        h[1] = (__bf16)__sinf(lx * wa.y + ly * wb.y);
        h[2] = (__bf16)__sinf(lx * wa.z + ly * wb.z);
        h[3] = (__bf16)__sinf(lx * wa.w + ly * wb.w);
    }
    for (int tl = tid; tl < 512; tl += 256) {
        int mm = m0 + tl; if (mm >= E) mm -= E;
        seg_s[tl] = (unsigned short)eidx[mm * 2];
        src_s[tl] = (unsigned short)eidx[mm * 2 + 1];
    }
    __syncthreads();

    {
        const int r  = tid >> 4;
        const int j0 = (tid & 15) * 4;
        float a0 = 0.f, a1 = 0.f, a2 = 0.f, a3 = 0.f;
        const __bf16* h1r = &h1b[r * H1_STR];
        #pragma unroll 8
        for (int k = 0; k < 64; ++k) {
            float h = (float)h1r[k];
            float4 w = *(const float4*)&w2[k * 64 + j0];
            a0 += h * w.x; a1 += h * w.y; a2 += h * w.z; a3 += h * w.w;
        }
        __bf16* h = &h2b[r * H2_STR + j0];
        h[0] = (__bf16)__sinf(a0);
        h[1] = (__bf16)__sinf(a1);
        h[2] = (__bf16)__sinf(a2);
        h[3] = (__bf16)__sinf(a3);
    }
    #pragma unroll 4
    for (int it = 0; it < 32; ++it) {
        int idx = it * 256 + tid;
        int b   = idx >> 9;
        int tl  = idx & 511;
        int mm  = m0 + tl;
        int cc  = ch0 + (mm >= E);
        if (mm >= E) mm -= E;
        float v = 0.f;
        if (cc < 32) v = feat[(b * 32 + cc) * N_IN + (int)src_s[tl]];
        gb[b * G_STR + tl] = (__bf16)v;
    }
    __syncthreads();

    const int lane = tid & 63;
    const int wv   = tid >> 6;
    const int ml   = lane & 15;
    const int q    = lane >> 4;

    {
        bf16x8 a0 = *(const bf16x8*)&h2b[ml * H2_STR + q * 8];
        bf16x8 a1 = *(const bf16x8*)&h2b[ml * H2_STR + 32 + q * 8];
        #pragma unroll
        for (int t = 0; t < 16; ++t) {
            int col = wv * 256 + t * 16 + ml;
            const __bf16* wp = &w3t[col * 64 + q * 8];
            bf16x8 b0 = *(const bf16x8*)wp;
            bf16x8 b1 = *(const bf16x8*)(wp + 32);
            f32x4 c = {0.f, 0.f, 0.f, 0.f};
            c = __builtin_amdgcn_mfma_f32_16x16x32_bf16(a0, b0, c, 0, 0, 0);
            c = __builtin_amdgcn_mfma_f32_16x16x32_bf16(a1, b1, c, 0, 0, 0);
            int i_ = col >> 5, j_ = col & 31;
            __bf16* fp = &ftv[j_ * FT_JSTR + i_];
            fp[(q * 4 + 0) * FB_FT_NSTR] = (__bf16)c[0];
            fp[(q * 4 + 1) * FB_FT_NSTR] = (__bf16)c[1];
            fp[(q * 4 + 2) * FB_FT_NSTR] = (__bf16)c[2];
            fp[(q * 4 + 3) * FB_FT_NSTR] = (__bf16)c[3];
        }
    }
    __syncthreads();

    {
        bf16x8 ag[4], f0[4], f1[4];
        #pragma unroll
        for (int rr = 0; rr < 4; ++rr) {
            int r = wv * 4 + rr;
            ag[rr] = *(const bf16x8*)&gb[ml * G_STR + r * 32 + q * 8];
            f0[rr] = *(const bf16x8*)&ftv[r * FB_FT_NSTR + ml        * FT_JSTR + q * 8];
            f1[rr] = *(const bf16x8*)&ftv[r * FB_FT_NSTR + (16 + ml) * FT_JSTR + q * 8];
        }
        __syncthreads();
        __bf16* valsb = ftv;
        #pragma unroll
        for (int rr = 0; rr < 4; ++rr) {
            int r = wv * 4 + rr;
            f32x4 c0 = {0.f, 0.f, 0.f, 0.f};
            f32x4 c1 = {0.f, 0.f, 0.f, 0.f};
            c0 = __builtin_amdgcn_mfma_f32_16x16x32_bf16(ag[rr], f0[rr], c0, 0, 0, 0);
            c1 = __builtin_amdgcn_mfma_f32_16x16x32_bf16(ag[rr], f1[rr], c1, 0, 0, 0);
            __bf16* vp = &valsb[r * 32];
            #pragma unroll
            for (int g_ = 0; g_ < 4; ++g_) {
                int b = q * 4 + g_;
                vp[b * V_STR + ml]      = (__bf16)c0[g_];
                vp[b * V_STR + 16 + ml] = (__bf16)c1[g_];
            }
        }
    }
    __syncthreads();

    {
        const __bf16* valsb = ftv;
        const int b = tid >> 4;
        const int r = tid & 15;
        const __bf16* vp = &valsb[b * V_STR + r * 32];
        bf16x8 v0 = *(const bf16x8*)(vp);
        bf16x8 v1 = *(const bf16x8*)(vp + 8);
        bf16x8 v2 = *(const bf16x8*)(vp + 16);
        bf16x8 v3 = *(const bf16x8*)(vp + 24);
        float vv[32];
        #pragma unroll
        for (int j = 0; j < 8; ++j) {
            vv[j]      = (float)v0[j];
            vv[8 + j]  = (float)v1[j];
            vv[16 + j] = (float)v2[j];
            vv[24 + j] = (float)v3[j];
        }
        const int tl0 = r * 32;
        int key_prev = -1;
        float acc = 0.f;
        #pragma unroll
        for (int j = 0; j < 32; ++j) {
            int mm = m0 + tl0 + j;
            int cc = ch0 + (mm >= E);
            if (mm >= E) mm -= E;
            if (cc < 32) {
                int o   = (int)seg_s[tl0 + j];
                int key = ((b * 32 + cc) << 10) | o;
                if (key != key_prev) {
                    if (key_prev >= 0) atomicAdd(&out[key_prev], acc);
                    key_prev = key;
                    acc = vv[j];
                } else {
                    acc += vv[j];
                }
            }
        }
        if (key_prev >= 0) atomicAdd(&out[key_prev], acc);
    }
}

extern "C" void kernel_launch(void* const* d_in, const int* in_sizes, int n_in,
                              void* d_out, int out_size, void* d_ws, size_t ws_size,
                              hipStream_t stream)
{
    (void)n_in;
    const float* feat = (const float*)d_in[0];
    const float* w1   = (const float*)d_in[1];
    const float* w2   = (const float*)d_in[2];
    const float* w3   = (const float*)d_in[3];
    const float* locs = (const float*)d_in[4];
    const int*   eidx = (const int*)d_in[5];
    float* out  = (float*)d_out;

    const int E = in_sizes[4] / 2;
    if (E <= 0) return;

    __bf16* w3t   = (__bf16*)((char*)d_ws + WS_W3T_OFF);
    __bf16* w2t   = (__bf16*)((char*)d_ws + WS_W2T_OFF);
    __bf16* featT = (__bf16*)((char*)d_ws + WS_FEATT_OFF);

    int nblocks = (E + ROWS - 1) / ROWS;

    if (ws_size >= (size_t)WS_NEED) {
        qc_prep2_kernel<<<1296, 256, 0, stream>>>(w3, w2, feat, out, w3t, w2t, featT);
        qc_fused_kernel<<<nblocks, 512, 0, stream>>>(featT, w1, locs, eidx, w2t, w3t, out, E);
    } else {
        int n4 = out_size / 4;
        qc_zero_kernel<<<(n4 + 255) / 256, 256, 0, stream>>>(out, n4);
        qc_prep_kernel<<<272, 256, 0, stream>>>(w3, w2, w3t, w2t);
        qc_main_kernel<<<nblocks, 256, 0, stream>>>(feat, w1, w2, locs, eidx, w3t, out, E);
    }
}

// Round 13
// 136.518 us; speedup vs baseline: 1.2111x; 1.2111x over previous
//
#include <hip/hip_runtime.h>
#include <hip/hip_bf16.h>

typedef __bf16 bf16x8  __attribute__((ext_vector_type(8)));
typedef __bf16 bf16x16 __attribute__((ext_vector_type(16)));
typedef float  f32x4   __attribute__((ext_vector_type(4)));

#define N_IN   4096
#define N_OUT  1024
#define BATCH  16
#define ROWS   16     // fallback kernel tile

// LDS strides in __bf16 elements
#define H1_STR   72
#define H2_STR   72
#define FT_JSTR  40     // i-stride inside a j-row
#define FTH_NSTR 640    // 16 j * 40 (per-row stride, half-j tile)
#define G_STR    520    // fallback
#define V_STR    520    // fallback
#define GSTR2    1032   // 1024 + 8 (32-row kernel: gb/vals stride)

// ws layout:
//   [0,131072)       w3t  bf16 (1024x64)       w3t[col*64+k]
//   [131072,139264)  w2t  bf16 (64x64)         w2t[col*64+k]
//   [139264,4333568) featT bf16 (32*4096*16)   featT[((c*4096+src)*16)+b]
#define WS_W3T_OFF    0
#define WS_W2T_OFF    131072
#define WS_FEATT_OFF  139264
#define WS_NEED       4333568

__global__ void qc_zero_kernel(float* __restrict__ out, int n4) {
    int i = blockIdx.x * blockDim.x + threadIdx.x;
    if (i < n4) ((float4*)out)[i] = make_float4(0.f, 0.f, 0.f, 0.f);
}

__global__ void qc_prep_kernel(const float* __restrict__ w3, const float* __restrict__ w2,
                               __bf16* __restrict__ w3t, __bf16* __restrict__ w2t) {
    int gid = blockIdx.x * blockDim.x + threadIdx.x;
    if (gid < 65536) {
        int k = gid & 63, col = gid >> 6;
        w3t[gid] = (__bf16)w3[k * 1024 + col];
    } else {
        int j = gid - 65536;
        int k = j & 63, col = j >> 6;
        w2t[j] = (__bf16)w2[k * 64 + col];
    }
}

// Fused prep: zero out (512 blks) + w3t (256) + w2t (16) + featT transpose (512)
__global__ void qc_prep2_kernel(const float* __restrict__ w3, const float* __restrict__ w2,
                                const float* __restrict__ feat,
                                float* __restrict__ out,
                                __bf16* __restrict__ w3t, __bf16* __restrict__ w2t,
                                __bf16* __restrict__ featT) {
    int bid = blockIdx.x, tid = threadIdx.x;
    if (bid < 512) {
        int i = bid * 256 + tid;
        ((float4*)out)[i] = make_float4(0.f, 0.f, 0.f, 0.f);
    } else if (bid < 768) {
        int gid = (bid - 512) * 256 + tid;
        int k = gid & 63, col = gid >> 6;
        w3t[gid] = (__bf16)w3[k * 1024 + col];
    } else if (bid < 784) {
        int j = (bid - 768) * 256 + tid;
        int k = j & 63, col = j >> 6;
        w2t[j] = (__bf16)w2[k * 64 + col];
    } else {
        int bid2 = bid - 784;                        // 0..511
        int c    = bid2 >> 4;                        // 0..31
        int src  = (bid2 & 15) * 256 + tid;          // 0..4095
        bf16x16 v;
        #pragma unroll
        for (int b = 0; b < 16; ++b)
            v[b] = (__bf16)feat[(b * 32 + c) * N_IN + src];
        __bf16* p = &featT[((size_t)c * N_IN + src) * 16];
        *(bf16x8*)p       = *(bf16x8*)&v;
        *(bf16x8*)(p + 8) = *((bf16x8*)&v + 1);
    }
}

// ---------------------------------------------------------------------------
// Fused 32-row kernel: 512 threads per 32-row tile, 1417 blocks.
// One 40960 B LDS region sequentially aliased: gb -> ftv(half-j) -> vals.
// ag (einsum A-frags) preloaded to registers so gb dies before C-pass0.
// Each w3t fragment feeds BOTH row-groups (2x reuse vs 16-row kernel).
// Phase E = R5-proven register run-merge + atomicAdd (atomics proven non-binding).
// ---------------------------------------------------------------------------
__global__ __launch_bounds__(512, 2)
void qc_fused32_kernel(const __bf16* __restrict__ featT,
                       const float* __restrict__ w1,
                       const float* __restrict__ locs,
                       const int*   __restrict__ eidx,
                       const __bf16* __restrict__ w2t,
                       const __bf16* __restrict__ w3t,
                       float* __restrict__ out,
                       int E)
{
    __shared__ __align__(16) unsigned char region1[40960]; // gb/ftv/vals
    __shared__ __align__(16) __bf16 h1b[32 * H1_STR];      // 4608 B
    __shared__ __align__(16) __bf16 h2b[32 * H2_STR];      // 4608 B
    __shared__ unsigned short seg_s[1024];                 // 2048 B
    // total 52224 B

    __bf16* gb   = (__bf16*)region1;   // [b][tl] stride GSTR2 (33024 B)
    __bf16* ftv  = (__bf16*)region1;   // [n:32][j:16][i:32+pad] (40960 B)
    __bf16* vals = (__bf16*)region1;   // [b][tl] stride GSTR2 (33024 B)

    const int tid = threadIdx.x;
    const int n0  = blockIdx.x * 32;
    const int t0  = n0 * 32;
    const int ch0 = t0 / E;
    const int m0  = t0 - ch0 * E;      // block spans <1024 t's -> at most one wrap

    // ---- Gather: 2 x 32B loads per thread (tl = tid, tid+512), issued first ----
    bf16x16 gvv[2];
    #pragma unroll
    for (int h = 0; h < 2; ++h) {
        int tl = tid + h * 512;
        int mm = m0 + tl;
        int cc = ch0 + (mm >= E);
        if (mm >= E) mm -= E;
        int2 p = ((const int2*)eidx)[mm];      // .x = seg, .y = src
        seg_s[tl] = (unsigned short)p.x;
        int ccc = cc < 32 ? cc : 31;
        bf16x16 g = *(const bf16x16*)&featT[((size_t)ccc * N_IN + p.y) * 16];
        if (cc >= 32) {
            #pragma unroll
            for (int z = 0; z < 16; ++z) g[z] = (__bf16)0.f;
        }
        gvv[h] = g;
    }

    // ---- Phase A: h1 = sin(loc @ W1); 32 rows x 64 cols, 4 cols/thread ----
    {
        const int r  = tid >> 4;               // 0..31
        const int j0 = (tid & 15) * 4;
        float lx = 0.f, ly = 0.f;
        int n = n0 + r;
        if (n < E) { lx = locs[n * 2]; ly = locs[n * 2 + 1]; }
        float4 wa = *(const float4*)&w1[j0];
        float4 wb = *(const float4*)&w1[64 + j0];
        __bf16* hp = &h1b[r * H1_STR + j0];
        hp[0] = (__bf16)__sinf(lx * wa.x + ly * wb.x);
        hp[1] = (__bf16)__sinf(lx * wa.y + ly * wb.y);
        hp[2] = (__bf16)__sinf(lx * wa.z + ly * wb.z);
        hp[3] = (__bf16)__sinf(lx * wa.w + ly * wb.w);
    }
    __syncthreads();   // S1

    const int lane = tid & 63;
    const int wv   = tid >> 6;      // 0..7
    const int ml   = lane & 15;
    const int q    = lane >> 4;

    // ---- Phase B: h2 = sin(h1 @ W2); all 8 waves (2 row-groups x 4 col-tiles) ----
    {
        const int rg = (wv >> 2) * 16;         // 0 or 16
        const int cw = (wv & 3) * 16;
        bf16x8 a0 = *(const bf16x8*)&h1b[(rg + ml) * H1_STR + q * 8];
        bf16x8 a1 = *(const bf16x8*)&h1b[(rg + ml) * H1_STR + 32 + q * 8];
        const __bf16* wp = &w2t[(cw + ml) * 64 + q * 8];
        bf16x8 b0 = *(const bf16x8*)wp;
        bf16x8 b1 = *(const bf16x8*)(wp + 32);
        f32x4 c = {0.f, 0.f, 0.f, 0.f};
        c = __builtin_amdgcn_mfma_f32_16x16x32_bf16(a0, b0, c, 0, 0, 0);
        c = __builtin_amdgcn_mfma_f32_16x16x32_bf16(a1, b1, c, 0, 0, 0);
        #pragma unroll
        for (int g_ = 0; g_ < 4; ++g_)
            h2b[(rg + q * 4 + g_) * H2_STR + cw + ml] = (__bf16)__sinf(c[g_]);
    }
    __syncthreads();   // S2

    // ---- Park gathered batches into gb ----
    #pragma unroll
    for (int b = 0; b < 16; ++b) {
        gb[b * GSTR2 + tid]       = gvv[0][b];
        gb[b * GSTR2 + 512 + tid] = gvv[1][b];
    }
    __syncthreads();   // S3

    // ---- Preload einsum A-frags (rows wv*4..+4) and h2 A-frags; then gb dies ----
    bf16x8 ag[4];
    #pragma unroll
    for (int rr = 0; rr < 4; ++rr)
        ag[rr] = *(const bf16x8*)&gb[ml * GSTR2 + (wv * 4 + rr) * 32 + q * 8];
    bf16x8 ha00 = *(const bf16x8*)&h2b[ml * H2_STR + q * 8];
    bf16x8 ha01 = *(const bf16x8*)&h2b[ml * H2_STR + 32 + q * 8];
    bf16x8 ha10 = *(const bf16x8*)&h2b[(16 + ml) * H2_STR + q * 8];
    bf16x8 ha11 = *(const bf16x8*)&h2b[(16 + ml) * H2_STR + 32 + q * 8];
    __syncthreads();   // S4 (gb dead; region becomes ftv)

    f32x4 c0[4], c1[4];

    // ---- C-pass0: filt cols j<16 for ALL 32 rows (w3t frag reused 2x) ----
    #pragma unroll
    for (int tt = 0; tt < 4; ++tt) {
        int i_  = wv * 4 + tt;                 // 0..31
        int col = i_ * 32 + ml;                // j = ml < 16
        const __bf16* wp = &w3t[col * 64 + q * 8];
        bf16x8 b0 = *(const bf16x8*)wp;
        bf16x8 b1 = *(const bf16x8*)(wp + 32);
        f32x4 cA = {0.f, 0.f, 0.f, 0.f};
        f32x4 cB = {0.f, 0.f, 0.f, 0.f};
        cA = __builtin_amdgcn_mfma_f32_16x16x32_bf16(ha00, b0, cA, 0, 0, 0);
        cA = __builtin_amdgcn_mfma_f32_16x16x32_bf16(ha01, b1, cA, 0, 0, 0);
        cB = __builtin_amdgcn_mfma_f32_16x16x32_bf16(ha10, b0, cB, 0, 0, 0);
        cB = __builtin_amdgcn_mfma_f32_16x16x32_bf16(ha11, b1, cB, 0, 0, 0);
        __bf16* fp = &ftv[ml * FT_JSTR + i_];
        #pragma unroll
        for (int g_ = 0; g_ < 4; ++g_) {
            fp[(q * 4 + g_) * FTH_NSTR]        = (__bf16)cA[g_];
            fp[(16 + q * 4 + g_) * FTH_NSTR]   = (__bf16)cB[g_];
        }
    }
    __syncthreads();   // S5

    // ---- D-pass0: vals j<16; wave handles rows wv*4..+4 ----
    {
        bf16x8 f[4];
        #pragma unroll
        for (int rr = 0; rr < 4; ++rr)
            f[rr] = *(const bf16x8*)&ftv[(wv * 4 + rr) * FTH_NSTR + ml * FT_JSTR + q * 8];
        #pragma unroll
        for (int rr = 0; rr < 4; ++rr) {
            f32x4 z = {0.f, 0.f, 0.f, 0.f};
            c0[rr] = __builtin_amdgcn_mfma_f32_16x16x32_bf16(ag[rr], f[rr], z, 0, 0, 0);
        }
    }
    __syncthreads();   // S6 (ftv reads done)

    // ---- C-pass1: filt cols j>=16 (overwrite ftv) ----
    #pragma unroll
    for (int tt = 0; tt < 4; ++tt) {
        int i_  = wv * 4 + tt;
        int col = i_ * 32 + 16 + ml;           // j = 16 + ml
        const __bf16* wp = &w3t[col * 64 + q * 8];
        bf16x8 b0 = *(const bf16x8*)wp;
        bf16x8 b1 = *(const bf16x8*)(wp + 32);
        f32x4 cA = {0.f, 0.f, 0.f, 0.f};
        f32x4 cB = {0.f, 0.f, 0.f, 0.f};
        cA = __builtin_amdgcn_mfma_f32_16x16x32_bf16(ha00, b0, cA, 0, 0, 0);
        cA = __builtin_amdgcn_mfma_f32_16x16x32_bf16(ha01, b1, cA, 0, 0, 0);
        cB = __builtin_amdgcn_mfma_f32_16x16x32_bf16(ha10, b0, cB, 0, 0, 0);
        cB = __builtin_amdgcn_mfma_f32_16x16x32_bf16(ha11, b1, cB, 0, 0, 0);
        __bf16* fp = &ftv[ml * FT_JSTR + i_];
        #pragma unroll
        for (int g_ = 0; g_ < 4; ++g_) {
            fp[(q * 4 + g_) * FTH_NSTR]        = (__bf16)cA[g_];
            fp[(16 + q * 4 + g_) * FTH_NSTR]   = (__bf16)cB[g_];
        }
    }
    __syncthreads();   // S7

    // ---- D-pass1 loads, then region becomes vals ----
    bf16x8 f1[4];
    #pragma unroll
    for (int rr = 0; rr < 4; ++rr)
        f1[rr] = *(const bf16x8*)&ftv[(wv * 4 + rr) * FTH_NSTR + ml * FT_JSTR + q * 8];
    __syncthreads();   // S8 (ftv dead; region becomes vals)
    #pragma unroll
    for (int rr = 0; rr < 4; ++rr) {
        f32x4 z = {0.f, 0.f, 0.f, 0.f};
        c1[rr] = __builtin_amdgcn_mfma_f32_16x16x32_bf16(ag[rr], f1[rr], z, 0, 0, 0);
    }
    #pragma unroll
    for (int rr = 0; rr < 4; ++rr) {
        int r = wv * 4 + rr;
        __bf16* vp = &vals[r * 32];
        #pragma unroll
        for (int g_ = 0; g_ < 4; ++g_) {
            int b = q * 4 + g_;
            vp[b * GSTR2 + ml]      = (__bf16)c0[rr][g_];
            vp[b * GSTR2 + 16 + ml] = (__bf16)c1[rr][g_];
        }
    }
    __syncthreads();   // S9

    // ---- Phase E: register run-merged atomic scatter (512 thr x 32 vals) ----
    {
        const int b   = tid >> 5;             // 0..15
        const int w   = tid & 31;
        const int tl0 = w * 32;
        const __bf16* vp = &vals[b * GSTR2 + tl0];
        bf16x8 v0 = *(const bf16x8*)(vp);
        bf16x8 v1 = *(const bf16x8*)(vp + 8);
        bf16x8 v2 = *(const bf16x8*)(vp + 16);
        bf16x8 v3 = *(const bf16x8*)(vp + 24);
        float vv[32];
        #pragma unroll
        for (int j = 0; j < 8; ++j) {
            vv[j]      = (float)v0[j];
            vv[8 + j]  = (float)v1[j];
            vv[16 + j] = (float)v2[j];
            vv[24 + j] = (float)v3[j];
        }
        int key_prev = -1;
        float acc = 0.f;
        #pragma unroll
        for (int j = 0; j < 32; ++j) {
            int mm2 = m0 + tl0 + j;
            int cc2 = ch0 + (mm2 >= E);
            if (cc2 < 32) {
                int o   = (int)seg_s[tl0 + j];
                int key = (cc2 << 10) | o;
                if (key != key_prev) {
                    if (key_prev >= 0) atomicAdd(&out[(b << 15) + key_prev], acc);
                    key_prev = key;
                    acc = vv[j];
                } else {
                    acc += vv[j];
                }
            }
        }
        if (key_prev >= 0) atomicAdd(&out[(b << 15) + key_prev], acc);
    }
}

// ---------------------------------------------------------------------------
// Fallback: round-1 fused kernel (used only if ws too small)
// ---------------------------------------------------------------------------
#define FB_FT_NSTR 1288
__global__ __launch_bounds__(256, 2)
void qc_main_kernel(const float* __restrict__ feat,
                    const float* __restrict__ w1,
                    const float* __restrict__ w2,
                    const float* __restrict__ locs,
                    const int*   __restrict__ eidx,
                    const __bf16* __restrict__ w3t,
                    float* __restrict__ out,
                    int E)
{
    __shared__ __align__(16) __bf16 h1b[ROWS * H1_STR];
    __shared__ __align__(16) __bf16 h2b[ROWS * H2_STR];
    __shared__ __align__(16) __bf16 ftv[ROWS * FB_FT_NSTR];
    __shared__ __align__(16) __bf16 gb [BATCH * G_STR];
    __shared__ unsigned short seg_s[512];
    __shared__ unsigned short src_s[512];

    const int tid = threadIdx.x;
    const int n0  = blockIdx.x * ROWS;
    const int t0  = n0 * 32;
    const int ch0 = t0 / E;
    const int m0  = t0 - ch0 * E;

    {
        const int r  = tid >> 4;
        const int j0 = (tid & 15) * 4;
        float lx = 0.f, ly = 0.f;
        int n = n0 + r;
        if (n < E) { lx = locs[n * 2]; ly = locs[n * 2 + 1]; }
        float4 wa = *(const float4*)&w1[j0];
        float4 wb = *(const float4*)&w1[64 + j0];
        __bf16* h = &h1b[r * H1_STR + j0];
        h[0] = (__bf16)__sinf(lx * wa.x + ly * wb.x);
        h[1] = (__bf16)__sinf(lx * wa.y + ly * wb.y);
        h[2] = (__bf16)__sinf(lx * wa.z + ly * wb.z);
        h[3] = (__bf16)__sinf(lx * wa.w + ly * wb.w);
    }
    for (int tl = tid; tl < 512; tl += 256) {
        int mm = m0 + tl; if (mm >= E) mm -= E;
        seg_s[tl] = (unsigned short)eidx[mm * 2];
        src_s[tl] = (unsigned short)eidx[mm * 2 + 1];
    }
    __syncthreads();

    {
        const int r  = tid >> 4;
        const int j0 = (tid & 15) * 4;
        float a0 = 0.f, a1 = 0.f, a2 = 0.f, a3 = 0.f;
        const __bf16* h1r = &h1b[r * H1_STR];
        #pragma unroll 8
        for (int k = 0; k < 64; ++k) {
            float h = (float)h1r[k];
            float4 w = *(const float4*)&w2[k * 64 + j0];
            a0 += h * w.x; a1 += h * w.y; a2 += h * w.z; a3 += h * w.w;
        }
        __bf16* h = &h2b[r * H2_STR + j0];
        h[0] = (__bf16)__sinf(a0);
        h[1] = (__bf16)__sinf(a1);
        h[2] = (__bf16)__sinf(a2);
        h[3] = (__bf16)__sinf(a3);
    }
    #pragma unroll 4
    for (int it = 0; it < 32; ++it) {
        int idx = it * 256 + tid;
        int b   = idx >> 9;
        int tl  = idx & 511;
        int mm  = m0 + tl;
        int cc  = ch0 + (mm >= E);
        if (mm >= E) mm -= E;
        float v = 0.f;
        if (cc < 32) v = feat[(b * 32 + cc) * N_IN + (int)src_s[tl]];
        gb[b * G_STR + tl] = (__bf16)v;
    }
    __syncthreads();

    const int lane = tid & 63;
    const int wv   = tid >> 6;
    const int ml   = lane & 15;
    const int q    = lane >> 4;

    {
        bf16x8 a0 = *(const bf16x8*)&h2b[ml * H2_STR + q * 8];
        bf16x8 a1 = *(const bf16x8*)&h2b[ml * H2_STR + 32 + q * 8];
        #pragma unroll
        for (int t = 0; t < 16; ++t) {
            int col = wv * 256 + t * 16 + ml;
            const __bf16* wp = &w3t[col * 64 + q * 8];
            bf16x8 b0 = *(const bf16x8*)wp;
            bf16x8 b1 = *(const bf16x8*)(wp + 32);
            f32x4 c = {0.f, 0.f, 0.f, 0.f};
            c = __builtin_amdgcn_mfma_f32_16x16x32_bf16(a0, b0, c, 0, 0, 0);
            c = __builtin_amdgcn_mfma_f32_16x16x32_bf16(a1, b1, c, 0, 0, 0);
            int i_ = col >> 5, j_ = col & 31;
            __bf16* fp = &ftv[j_ * FT_JSTR + i_];
            fp[(q * 4 + 0) * FB_FT_NSTR] = (__bf16)c[0];
            fp[(q * 4 + 1) * FB_FT_NSTR] = (__bf16)c[1];
            fp[(q * 4 + 2) * FB_FT_NSTR] = (__bf16)c[2];
            fp[(q * 4 + 3) * FB_FT_NSTR] = (__bf16)c[3];
        }
    }
    __syncthreads();

    {
        bf16x8 ag[4], f0[4], f1[4];
        #pragma unroll
        for (int rr = 0; rr < 4; ++rr) {
            int r = wv * 4 + rr;
            ag[rr] = *(const bf16x8*)&gb[ml * G_STR + r * 32 + q * 8];
            f0[rr] = *(const bf16x8*)&ftv[r * FB_FT_NSTR + ml        * FT_JSTR + q * 8];
            f1[rr] = *(const bf16x8*)&ftv[r * FB_FT_NSTR + (16 + ml) * FT_JSTR + q * 8];
        }
        __syncthreads();
        __bf16* valsb = ftv;
        #pragma unroll
        for (int rr = 0; rr < 4; ++rr) {
            int r = wv * 4 + rr;
            f32x4 c0 = {0.f, 0.f, 0.f, 0.f};
            f32x4 c1 = {0.f, 0.f, 0.f, 0.f};
            c0 = __builtin_amdgcn_mfma_f32_16x16x32_bf16(ag[rr], f0[rr], c0, 0, 0, 0);
            c1 = __builtin_amdgcn_mfma_f32_16x16x32_bf16(ag[rr], f1[rr], c1, 0, 0, 0);
            __bf16* vp = &valsb[r * 32];
            #pragma unroll
            for (int g_ = 0; g_ < 4; ++g_) {
                int b = q * 4 + g_;
                vp[b * V_STR + ml]      = (__bf16)c0[g_];
                vp[b * V_STR + 16 + ml] = (__bf16)c1[g_];
            }
        }
    }
    __syncthreads();

    {
        const __bf16* valsb = ftv;
        const int b = tid >> 4;
        const int r = tid & 15;
        const __bf16* vp = &valsb[b * V_STR + r * 32];
        bf16x8 v0 = *(const bf16x8*)(vp);
        bf16x8 v1 = *(const bf16x8*)(vp + 8);
        bf16x8 v2 = *(const bf16x8*)(vp + 16);
        bf16x8 v3 = *(const bf16x8*)(vp + 24);
        float vv[32];
        #pragma unroll
        for (int j = 0; j < 8; ++j) {
            vv[j]      = (float)v0[j];
            vv[8 + j]  = (float)v1[j];
            vv[16 + j] = (float)v2[j];
            vv[24 + j] = (float)v3[j];
        }
        const int tl0 = r * 32;
        int key_prev = -1;
        float acc = 0.f;
        #pragma unroll
        for (int j = 0; j < 32; ++j) {
            int mm = m0 + tl0 + j;
            int cc = ch0 + (mm >= E);
            if (mm >= E) mm -= E;
            if (cc < 32) {
                int o   = (int)seg_s[tl0 + j];
                int key = ((b * 32 + cc) << 10) | o;
                if (key != key_prev) {
                    if (key_prev >= 0) atomicAdd(&out[key_prev], acc);
                    key_prev = key;
                    acc = vv[j];
                } else {
                    acc += vv[j];
                }
            }
        }
        if (key_prev >= 0) atomicAdd(&out[key_prev], acc);
    }
}

extern "C" void kernel_launch(void* const* d_in, const int* in_sizes, int n_in,
                              void* d_out, int out_size, void* d_ws, size_t ws_size,
                              hipStream_t stream)
{
    (void)n_in;
    const float* feat = (const float*)d_in[0];
    const float* w1   = (const float*)d_in[1];
    const float* w2   = (const float*)d_in[2];
    const float* w3   = (const float*)d_in[3];
    const float* locs = (const float*)d_in[4];
    const int*   eidx = (const int*)d_in[5];
    float* out  = (float*)d_out;

    const int E = in_sizes[4] / 2;
    if (E <= 0) return;

    __bf16* w3t   = (__bf16*)((char*)d_ws + WS_W3T_OFF);
    __bf16* w2t   = (__bf16*)((char*)d_ws + WS_W2T_OFF);
    __bf16* featT = (__bf16*)((char*)d_ws + WS_FEATT_OFF);

    if (ws_size >= (size_t)WS_NEED) {
        int nblocks = (E + 31) / 32;
        qc_prep2_kernel<<<1296, 256, 0, stream>>>(w3, w2, feat, out, w3t, w2t, featT);
        qc_fused32_kernel<<<nblocks, 512, 0, stream>>>(featT, w1, locs, eidx, w2t, w3t, out, E);
    } else {
        int n4 = out_size / 4;
        int nblocks = (E + ROWS - 1) / ROWS;
        qc_zero_kernel<<<(n4 + 255) / 256, 256, 0, stream>>>(out, n4);
        qc_prep_kernel<<<272, 256, 0, stream>>>(w3, w2, w3t, w2t);
        qc_main_kernel<<<nblocks, 256, 0, stream>>>(feat, w1, w2, locs, eidx, w3t, out, E);
    }
}

// Round 14
// 135.676 us; speedup vs baseline: 1.2186x; 1.0062x over previous
//
#include <hip/hip_runtime.h>
#include <hip/hip_bf16.h>

typedef __bf16 bf16x4  __attribute__((ext_vector_type(4)));
typedef __bf16 bf16x8  __attribute__((ext_vector_type(8)));
typedef __bf16 bf16x16 __attribute__((ext_vector_type(16)));
typedef float  f32x4   __attribute__((ext_vector_type(4)));

#define N_IN   4096
#define N_OUT  1024
#define BATCH  16
#define ROWS   16     // fallback kernel tile

// LDS strides in __bf16 elements
#define H1_STR   72
#define H2_STR   72
#define FT_JSTR  40     // i-stride inside a j-slot row (fallback + 32-row)
#define FTH_NSTR 648    // 32-row kernel: per-n stride (16 j * 40 + 8 pad)
#define G_STR    520    // fallback
#define V_STR    520    // fallback
#define GSTR2    1048   // 32-row kernel gb stride (1024 + 24)
#define VSTR2    1288   // 32-row kernel vals per-b stride (32 w * 40)
#define FB_FT_NSTR 1288 // fallback

// ws layout:
//   [0,131072)       w3t  bf16 (1024x64)       w3t[col*64+k]
//   [131072,139264)  w2t  bf16 (64x64)         w2t[col*64+k]
//   [139264,4333568) featT bf16 (32*4096*16)   featT[((c*4096+src)*16)+b]
#define WS_W3T_OFF    0
#define WS_W2T_OFF    131072
#define WS_FEATT_OFF  139264
#define WS_NEED       4333568

__global__ void qc_zero_kernel(float* __restrict__ out, int n4) {
    int i = blockIdx.x * blockDim.x + threadIdx.x;
    if (i < n4) ((float4*)out)[i] = make_float4(0.f, 0.f, 0.f, 0.f);
}

__global__ void qc_prep_kernel(const float* __restrict__ w3, const float* __restrict__ w2,
                               __bf16* __restrict__ w3t, __bf16* __restrict__ w2t) {
    int gid = blockIdx.x * blockDim.x + threadIdx.x;
    if (gid < 65536) {
        int k = gid & 63, col = gid >> 6;
        w3t[gid] = (__bf16)w3[k * 1024 + col];
    } else {
        int j = gid - 65536;
        int k = j & 63, col = j >> 6;
        w2t[j] = (__bf16)w2[k * 64 + col];
    }
}

// Fused prep: zero out (512 blks) + w3t (256) + w2t (16) + featT transpose (512)
__global__ void qc_prep2_kernel(const float* __restrict__ w3, const float* __restrict__ w2,
                                const float* __restrict__ feat,
                                float* __restrict__ out,
                                __bf16* __restrict__ w3t, __bf16* __restrict__ w2t,
                                __bf16* __restrict__ featT) {
    int bid = blockIdx.x, tid = threadIdx.x;
    if (bid < 512) {
        int i = bid * 256 + tid;
        ((float4*)out)[i] = make_float4(0.f, 0.f, 0.f, 0.f);
    } else if (bid < 768) {
        int gid = (bid - 512) * 256 + tid;
        int k = gid & 63, col = gid >> 6;
        w3t[gid] = (__bf16)w3[k * 1024 + col];
    } else if (bid < 784) {
        int j = (bid - 768) * 256 + tid;
        int k = j & 63, col = j >> 6;
        w2t[j] = (__bf16)w2[k * 64 + col];
    } else {
        int bid2 = bid - 784;                        // 0..511
        int c    = bid2 >> 4;                        // 0..31
        int src  = (bid2 & 15) * 256 + tid;          // 0..4095
        bf16x16 v;
        #pragma unroll
        for (int b = 0; b < 16; ++b)
            v[b] = (__bf16)feat[(b * 32 + c) * N_IN + src];
        __bf16* p = &featT[((size_t)c * N_IN + src) * 16];
        *(bf16x8*)p       = *(bf16x8*)&v;
        *(bf16x8*)(p + 8) = *((bf16x8*)&v + 1);
    }
}

// ---------------------------------------------------------------------------
// Fused 32-row kernel (R13 structure) with bank-conflict fixes:
//   - C-pass accumulates 4 i-values in registers -> 8x ds_write_b64
//     (was 64 b16 stores at 8-way conflict)
//   - ftv n-stride 648 (q-spread, 16B-aligned b128 reads)
//   - vals laid out [b][w*40+j] (VSTR2=1288): phase-E b128 reads spread
//     over 16 bank-groups (was 2 -> ~16-way conflict)
//   - gb stride 1048 (ag-read bank spread)
// ---------------------------------------------------------------------------
__global__ __launch_bounds__(512, 2)
void qc_fused32_kernel(const __bf16* __restrict__ featT,
                       const float* __restrict__ w1,
                       const float* __restrict__ locs,
                       const int*   __restrict__ eidx,
                       const __bf16* __restrict__ w2t,
                       const __bf16* __restrict__ w3t,
                       float* __restrict__ out,
                       int E)
{
    __shared__ __align__(16) unsigned char region1[41472]; // gb/ftv/vals
    __shared__ __align__(16) __bf16 h1b[32 * H1_STR];      // 4608 B
    __shared__ __align__(16) __bf16 h2b[32 * H2_STR];      // 4608 B
    __shared__ unsigned short seg_s[1024];                 // 2048 B
    // total 52736 B -> 2 blocks/CU

    __bf16* gb   = (__bf16*)region1;   // [b][tl] stride GSTR2   (33536 B)
    __bf16* ftv  = (__bf16*)region1;   // [n:32][jslot:16*40+8]  (41472 B)
    __bf16* vals = (__bf16*)region1;   // [b][w*40+j] stride VSTR2 (41216 B)

    const int tid = threadIdx.x;
    const int n0  = blockIdx.x * 32;
    const int t0  = n0 * 32;
    const int ch0 = t0 / E;
    const int m0  = t0 - ch0 * E;      // block spans <1024 t's -> at most one wrap

    // ---- Gather: 2 x 32B loads per thread (tl = tid, tid+512), issued first ----
    bf16x16 gvv[2];
    #pragma unroll
    for (int h = 0; h < 2; ++h) {
        int tl = tid + h * 512;
        int mm = m0 + tl;
        int cc = ch0 + (mm >= E);
        if (mm >= E) mm -= E;
        int2 p = ((const int2*)eidx)[mm];      // .x = seg, .y = src
        seg_s[tl] = (unsigned short)p.x;
        int ccc = cc < 32 ? cc : 31;
        bf16x16 g = *(const bf16x16*)&featT[((size_t)ccc * N_IN + p.y) * 16];
        if (cc >= 32) {
            #pragma unroll
            for (int z = 0; z < 16; ++z) g[z] = (__bf16)0.f;
        }
        gvv[h] = g;
    }

    // ---- Phase A: h1 = sin(loc @ W1); 32 rows x 64 cols, 4 cols/thread ----
    {
        const int r  = tid >> 4;               // 0..31
        const int j0 = (tid & 15) * 4;
        float lx = 0.f, ly = 0.f;
        int n = n0 + r;
        if (n < E) { lx = locs[n * 2]; ly = locs[n * 2 + 1]; }
        float4 wa = *(const float4*)&w1[j0];
        float4 wb = *(const float4*)&w1[64 + j0];
        __bf16* hp = &h1b[r * H1_STR + j0];
        hp[0] = (__bf16)__sinf(lx * wa.x + ly * wb.x);
        hp[1] = (__bf16)__sinf(lx * wa.y + ly * wb.y);
        hp[2] = (__bf16)__sinf(lx * wa.z + ly * wb.z);
        hp[3] = (__bf16)__sinf(lx * wa.w + ly * wb.w);
    }
    __syncthreads();   // S1

    const int lane = tid & 63;
    const int wv   = tid >> 6;      // 0..7
    const int ml   = lane & 15;
    const int q    = lane >> 4;

    // ---- Phase B: h2 = sin(h1 @ W2); all 8 waves (2 row-groups x 4 col-tiles) ----
    {
        const int rg = (wv >> 2) * 16;         // 0 or 16
        const int cw = (wv & 3) * 16;
        bf16x8 a0 = *(const bf16x8*)&h1b[(rg + ml) * H1_STR + q * 8];
        bf16x8 a1 = *(const bf16x8*)&h1b[(rg + ml) * H1_STR + 32 + q * 8];
        const __bf16* wp = &w2t[(cw + ml) * 64 + q * 8];
        bf16x8 b0 = *(const bf16x8*)wp;
        bf16x8 b1 = *(const bf16x8*)(wp + 32);
        f32x4 c = {0.f, 0.f, 0.f, 0.f};
        c = __builtin_amdgcn_mfma_f32_16x16x32_bf16(a0, b0, c, 0, 0, 0);
        c = __builtin_amdgcn_mfma_f32_16x16x32_bf16(a1, b1, c, 0, 0, 0);
        #pragma unroll
        for (int g_ = 0; g_ < 4; ++g_)
            h2b[(rg + q * 4 + g_) * H2_STR + cw + ml] = (__bf16)__sinf(c[g_]);
    }
    __syncthreads();   // S2

    // ---- Park gathered batches into gb ----
    #pragma unroll
    for (int b = 0; b < 16; ++b) {
        gb[b * GSTR2 + tid]       = gvv[0][b];
        gb[b * GSTR2 + 512 + tid] = gvv[1][b];
    }
    __syncthreads();   // S3

    // ---- Preload einsum A-frags (rows wv*4..+4) and h2 A-frags; then gb dies ----
    bf16x8 ag[4];
    #pragma unroll
    for (int rr = 0; rr < 4; ++rr)
        ag[rr] = *(const bf16x8*)&gb[ml * GSTR2 + (wv * 4 + rr) * 32 + q * 8];
    bf16x8 ha00 = *(const bf16x8*)&h2b[ml * H2_STR + q * 8];
    bf16x8 ha01 = *(const bf16x8*)&h2b[ml * H2_STR + 32 + q * 8];
    bf16x8 ha10 = *(const bf16x8*)&h2b[(16 + ml) * H2_STR + q * 8];
    bf16x8 ha11 = *(const bf16x8*)&h2b[(16 + ml) * H2_STR + 32 + q * 8];
    __syncthreads();   // S4 (gb dead; region becomes ftv)

    f32x4 c0[4], c1[4];

    // ---- C-pass0: filt cols j<16, acc in regs, 8x b64 writes ----
    {
        f32x4 accA[4], accB[4];
        #pragma unroll
        for (int tt = 0; tt < 4; ++tt) {
            int i_  = wv * 4 + tt;
            int col = i_ * 32 + ml;            // j = ml < 16
            const __bf16* wp = &w3t[col * 64 + q * 8];
            bf16x8 b0 = *(const bf16x8*)wp;
            bf16x8 b1 = *(const bf16x8*)(wp + 32);
            f32x4 cA = {0.f, 0.f, 0.f, 0.f};
            f32x4 cB = {0.f, 0.f, 0.f, 0.f};
            cA = __builtin_amdgcn_mfma_f32_16x16x32_bf16(ha00, b0, cA, 0, 0, 0);
            cA = __builtin_amdgcn_mfma_f32_16x16x32_bf16(ha01, b1, cA, 0, 0, 0);
            cB = __builtin_amdgcn_mfma_f32_16x16x32_bf16(ha10, b0, cB, 0, 0, 0);
            cB = __builtin_amdgcn_mfma_f32_16x16x32_bf16(ha11, b1, cB, 0, 0, 0);
            accA[tt] = cA; accB[tt] = cB;
        }
        #pragma unroll
        for (int g_ = 0; g_ < 4; ++g_) {
            bf16x4 pa, pb;
            #pragma unroll
            for (int tt = 0; tt < 4; ++tt) {
                pa[tt] = (__bf16)accA[tt][g_];
                pb[tt] = (__bf16)accB[tt][g_];
            }
            *(bf16x4*)&ftv[(q * 4 + g_) * FTH_NSTR + ml * FT_JSTR + wv * 4]        = pa;
            *(bf16x4*)&ftv[(16 + q * 4 + g_) * FTH_NSTR + ml * FT_JSTR + wv * 4]   = pb;
        }
    }
    __syncthreads();   // S5

    // ---- D-pass0: vals j<16; wave handles rows wv*4..+4 ----
    {
        bf16x8 f[4];
        #pragma unroll
        for (int rr = 0; rr < 4; ++rr)
            f[rr] = *(const bf16x8*)&ftv[(wv * 4 + rr) * FTH_NSTR + ml * FT_JSTR + q * 8];
        #pragma unroll
        for (int rr = 0; rr < 4; ++rr) {
            f32x4 z = {0.f, 0.f, 0.f, 0.f};
            c0[rr] = __builtin_amdgcn_mfma_f32_16x16x32_bf16(ag[rr], f[rr], z, 0, 0, 0);
        }
    }
    __syncthreads();   // S6 (ftv reads done)

    // ---- C-pass1: filt cols j>=16 (overwrite ftv), same reg-acc scheme ----
    {
        f32x4 accA[4], accB[4];
        #pragma unroll
        for (int tt = 0; tt < 4; ++tt) {
            int i_  = wv * 4 + tt;
            int col = i_ * 32 + 16 + ml;       // j = 16 + ml
            const __bf16* wp = &w3t[col * 64 + q * 8];
            bf16x8 b0 = *(const bf16x8*)wp;
            bf16x8 b1 = *(const bf16x8*)(wp + 32);
            f32x4 cA = {0.f, 0.f, 0.f, 0.f};
            f32x4 cB = {0.f, 0.f, 0.f, 0.f};
            cA = __builtin_amdgcn_mfma_f32_16x16x32_bf16(ha00, b0, cA, 0, 0, 0);
            cA = __builtin_amdgcn_mfma_f32_16x16x32_bf16(ha01, b1, cA, 0, 0, 0);
            cB = __builtin_amdgcn_mfma_f32_16x16x32_bf16(ha10, b0, cB, 0, 0, 0);
            cB = __builtin_amdgcn_mfma_f32_16x16x32_bf16(ha11, b1, cB, 0, 0, 0);
            accA[tt] = cA; accB[tt] = cB;
        }
        #pragma unroll
        for (int g_ = 0; g_ < 4; ++g_) {
            bf16x4 pa, pb;
            #pragma unroll
            for (int tt = 0; tt < 4; ++tt) {
                pa[tt] = (__bf16)accA[tt][g_];
                pb[tt] = (__bf16)accB[tt][g_];
            }
            *(bf16x4*)&ftv[(q * 4 + g_) * FTH_NSTR + ml * FT_JSTR + wv * 4]        = pa;
            *(bf16x4*)&ftv[(16 + q * 4 + g_) * FTH_NSTR + ml * FT_JSTR + wv * 4]   = pb;
        }
    }
    __syncthreads();   // S7

    // ---- D-pass1 loads, then region becomes vals ----
    bf16x8 f1[4];
    #pragma unroll
    for (int rr = 0; rr < 4; ++rr)
        f1[rr] = *(const bf16x8*)&ftv[(wv * 4 + rr) * FTH_NSTR + ml * FT_JSTR + q * 8];
    __syncthreads();   // S8 (ftv dead; region becomes vals)
    #pragma unroll
    for (int rr = 0; rr < 4; ++rr) {
        f32x4 z = {0.f, 0.f, 0.f, 0.f};
        c1[rr] = __builtin_amdgcn_mfma_f32_16x16x32_bf16(ag[rr], f1[rr], z, 0, 0, 0);
    }
    #pragma unroll
    for (int rr = 0; rr < 4; ++rr) {
        int r = wv * 4 + rr;                   // r == window index w
        __bf16* vp = &vals[r * FT_JSTR];       // per-w stride 40
        #pragma unroll
        for (int g_ = 0; g_ < 4; ++g_) {
            int b = q * 4 + g_;
            vp[b * VSTR2 + ml]      = (__bf16)c0[rr][g_];
            vp[b * VSTR2 + 16 + ml] = (__bf16)c1[rr][g_];
        }
    }
    __syncthreads();   // S9

    // ---- Phase E: register run-merged atomic scatter (512 thr x 32 vals) ----
    {
        const int b   = tid >> 5;             // 0..15
        const int w   = tid & 31;
        const int tl0 = w * 32;
        const __bf16* vp = &vals[b * VSTR2 + w * FT_JSTR];
        bf16x8 v0 = *(const bf16x8*)(vp);
        bf16x8 v1 = *(const bf16x8*)(vp + 8);
        bf16x8 v2 = *(const bf16x8*)(vp + 16);
        bf16x8 v3 = *(const bf16x8*)(vp + 24);
        float vv[32];
        #pragma unroll
        for (int j = 0; j < 8; ++j) {
            vv[j]      = (float)v0[j];
            vv[8 + j]  = (float)v1[j];
            vv[16 + j] = (float)v2[j];
            vv[24 + j] = (float)v3[j];
        }
        int key_prev = -1;
        float acc = 0.f;
        #pragma unroll
        for (int j = 0; j < 32; ++j) {
            int mm2 = m0 + tl0 + j;
            int cc2 = ch0 + (mm2 >= E);
            if (cc2 < 32) {
                int o   = (int)seg_s[tl0 + j];
                int key = (cc2 << 10) | o;
                if (key != key_prev) {
                    if (key_prev >= 0) atomicAdd(&out[(b << 15) + key_prev], acc);
                    key_prev = key;
                    acc = vv[j];
                } else {
                    acc += vv[j];
                }
            }
        }
        if (key_prev >= 0) atomicAdd(&out[(b << 15) + key_prev], acc);
    }
}

// ---------------------------------------------------------------------------
// Fallback: round-1 fused kernel (used only if ws too small)
// ---------------------------------------------------------------------------
__global__ __launch_bounds__(256, 2)
void qc_main_kernel(const float* __restrict__ feat,
                    const float* __restrict__ w1,
                    const float* __restrict__ w2,
                    const float* __restrict__ locs,
                    const int*   __restrict__ eidx,
                    const __bf16* __restrict__ w3t,
                    float* __restrict__ out,
                    int E)
{
    __shared__ __align__(16) __bf16 h1b[ROWS * H1_STR];
    __shared__ __align__(16) __bf16 h2b[ROWS * H2_STR];
    __shared__ __align__(16) __bf16 ftv[ROWS * FB_FT_NSTR];
    __shared__ __align__(16) __bf16 gb [BATCH * G_STR];
    __shared__ unsigned short seg_s[512];
    __shared__ unsigned short src_s[512];

    const int tid = threadIdx.x;
    const int n0  = blockIdx.x * ROWS;
    const int t0  = n0 * 32;
    const int ch0 = t0 / E;
    const int m0  = t0 - ch0 * E;

    {
        const int r  = tid >> 4;
        const int j0 = (tid & 15) * 4;
        float lx = 0.f, ly = 0.f;
        int n = n0 + r;
        if (n < E) { lx = locs[n * 2]; ly = locs[n * 2 + 1]; }
        float4 wa = *(const float4*)&w1[j0];
        float4 wb = *(const float4*)&w1[64 + j0];
        __bf16* h = &h1b[r * H1_STR + j0];
        h[0] = (__bf16)__sinf(lx * wa.x + ly * wb.x);
        h[1] = (__bf16)__sinf(lx * wa.y + ly * wb.y);
        h[2] = (__bf16)__sinf(lx * wa.z + ly * wb.z);
        h[3] = (__bf16)__sinf(lx * wa.w + ly * wb.w);
    }
    for (int tl = tid; tl < 512; tl += 256) {
        int mm = m0 + tl; if (mm >= E) mm -= E;
        seg_s[tl] = (unsigned short)eidx[mm * 2];
        src_s[tl] = (unsigned short)eidx[mm * 2 + 1];
    }
    __syncthreads();

    {
        const int r  = tid >> 4;
        const int j0 = (tid & 15) * 4;
        float a0 = 0.f, a1 = 0.f, a2 = 0.f, a3 = 0.f;
        const __bf16* h1r = &h1b[r * H1_STR];
        #pragma unroll 8
        for (int k = 0; k < 64; ++k) {
            float h = (float)h1r[k];
            float4 w = *(const float4*)&w2[k * 64 + j0];
            a0 += h * w.x; a1 += h * w.y; a2 += h * w.z; a3 += h * w.w;
        }
        __bf16* h = &h2b[r * H2_STR + j0];
        h[0] = (__bf16)__sinf(a0);
        h[1] = (__bf16)__sinf(a1);
        h[2] = (__bf16)__sinf(a2);
        h[3] = (__bf16)__sinf(a3);
    }
    #pragma unroll 4
    for (int it = 0; it < 32; ++it) {
        int idx = it * 256 + tid;
        int b   = idx >> 9;
        int tl  = idx & 511;
        int mm  = m0 + tl;
        int cc  = ch0 + (mm >= E);
        if (mm >= E) mm -= E;
        float v = 0.f;
        if (cc < 32) v = feat[(b * 32 + cc) * N_IN + (int)src_s[tl]];
        gb[b * G_STR + tl] = (__bf16)v;
    }
    __syncthreads();

    const int lane = tid & 63;
    const int wv   = tid >> 6;
    const int ml   = lane & 15;
    const int q    = lane >> 4;

    {
        bf16x8 a0 = *(const bf16x8*)&h2b[ml * H2_STR + q * 8];
        bf16x8 a1 = *(const bf16x8*)&h2b[ml * H2_STR + 32 + q * 8];
        #pragma unroll
        for (int t = 0; t < 16; ++t) {
            int col = wv * 256 + t * 16 + ml;
            const __bf16* wp = &w3t[col * 64 + q * 8];
            bf16x8 b0 = *(const bf16x8*)wp;
            bf16x8 b1 = *(const bf16x8*)(wp + 32);
            f32x4 c = {0.f, 0.f, 0.f, 0.f};
            c = __builtin_amdgcn_mfma_f32_16x16x32_bf16(a0, b0, c, 0, 0, 0);
            c = __builtin_amdgcn_mfma_f32_16x16x32_bf16(a1, b1, c, 0, 0, 0);
            int i_ = col >> 5, j_ = col & 31;
            __bf16* fp = &ftv[j_ * FT_JSTR + i_];
            fp[(q * 4 + 0) * FB_FT_NSTR] = (__bf16)c[0];
            fp[(q * 4 + 1) * FB_FT_NSTR] = (__bf16)c[1];
            fp[(q * 4 + 2) * FB_FT_NSTR] = (__bf16)c[2];
            fp[(q * 4 + 3) * FB_FT_NSTR] = (__bf16)c[3];
        }
    }
    __syncthreads();

    {
        bf16x8 ag[4], f0[4], f1[4];
        #pragma unroll
        for (int rr = 0; rr < 4; ++rr) {
            int r = wv * 4 + rr;
            ag[rr] = *(const bf16x8*)&gb[ml * G_STR + r * 32 + q * 8];
            f0[rr] = *(const bf16x8*)&ftv[r * FB_FT_NSTR + ml        * FT_JSTR + q * 8];
            f1[rr] = *(const bf16x8*)&ftv[r * FB_FT_NSTR + (16 + ml) * FT_JSTR + q * 8];
        }
        __syncthreads();
        __bf16* valsb = ftv;
        #pragma unroll
        for (int rr = 0; rr < 4; ++rr) {
            int r = wv * 4 + rr;
            f32x4 c0 = {0.f, 0.f, 0.f, 0.f};
            f32x4 c1 = {0.f, 0.f, 0.f, 0.f};
            c0 = __builtin_amdgcn_mfma_f32_16x16x32_bf16(ag[rr], f0[rr], c0, 0, 0, 0);
            c1 = __builtin_amdgcn_mfma_f32_16x16x32_bf16(ag[rr], f1[rr], c1, 0, 0, 0);
            __bf16* vp = &valsb[r * 32];
            #pragma unroll
            for (int g_ = 0; g_ < 4; ++g_) {
                int b = q * 4 + g_;
                vp[b * V_STR + ml]      = (__bf16)c0[g_];
                vp[b * V_STR + 16 + ml] = (__bf16)c1[g_];
            }
        }
    }
    __syncthreads();

    {
        const __bf16* valsb = ftv;
        const int b = tid >> 4;
        const int r = tid & 15;
        const __bf16* vp = &valsb[b * V_STR + r * 32];
        bf16x8 v0 = *(const bf16x8*)(vp);
        bf16x8 v1 = *(const bf16x8*)(vp + 8);
        bf16x8 v2 = *(const bf16x8*)(vp + 16);
        bf16x8 v3 = *(const bf16x8*)(vp + 24);
        float vv[32];
        #pragma unroll
        for (int j = 0; j < 8; ++j) {
            vv[j]      = (float)v0[j];
            vv[8 + j]  = (float)v1[j];
            vv[16 + j] = (float)v2[j];
            vv[24 + j] = (float)v3[j];
        }
        const int tl0 = r * 32;
        int key_prev = -1;
        float acc = 0.f;
        #pragma unroll
        for (int j = 0; j < 32; ++j) {
            int mm = m0 + tl0 + j;
            int cc = ch0 + (mm >= E);
            if (mm >= E) mm -= E;
            if (cc < 32) {
                int o   = (int)seg_s[tl0 + j];
                int key = ((b * 32 + cc) << 10) | o;
                if (key != key_prev) {
                    if (key_prev >= 0) atomicAdd(&out[key_prev], acc);
                    key_prev = key;
                    acc = vv[j];
                } else {
                    acc += vv[j];
                }
            }
        }
        if (key_prev >= 0) atomicAdd(&out[key_prev], acc);
    }
}

extern "C" void kernel_launch(void* const* d_in, const int* in_sizes, int n_in,
                              void* d_out, int out_size, void* d_ws, size_t ws_size,
                              hipStream_t stream)
{
    (void)n_in;
    const float* feat = (const float*)d_in[0];
    const float* w1   = (const float*)d_in[1];
    const float* w2   = (const float*)d_in[2];
    const float* w3   = (const float*)d_in[3];
    const float* locs = (const float*)d_in[4];
    const int*   eidx = (const int*)d_in[5];
    float* out  = (float*)d_out;

    const int E = in_sizes[4] / 2;
    if (E <= 0) return;

    __bf16* w3t   = (__bf16*)((char*)d_ws + WS_W3T_OFF);
    __bf16* w2t   = (__bf16*)((char*)d_ws + WS_W2T_OFF);
    __bf16* featT = (__bf16*)((char*)d_ws + WS_FEATT_OFF);

    if (ws_size >= (size_t)WS_NEED) {
        int nblocks = (E + 31) / 32;
        qc_prep2_kernel<<<1296, 256, 0, stream>>>(w3, w2, feat, out, w3t, w2t, featT);
        qc_fused32_kernel<<<nblocks, 512, 0, stream>>>(featT, w1, locs, eidx, w2t, w3t, out, E);
    } else {
        int n4 = out_size / 4;
        int nblocks = (E + ROWS - 1) / ROWS;
        qc_zero_kernel<<<(n4 + 255) / 256, 256, 0, stream>>>(out, n4);
        qc_prep_kernel<<<272, 256, 0, stream>>>(w3, w2, w3t, w2t);
        qc_main_kernel<<<nblocks, 256, 0, stream>>>(feat, w1, w2, locs, eidx, w3t, out, E);
    }
}